// Round 1
// baseline (1032.601 us; speedup 1.0000x reference)
//
#include <hip/hip_runtime.h>
#include <math.h>

#define NB 2
#define NC 64
#define NN 32768
#define NK 16
#define NPTS (NB*NN)   // 65536

// ---------------------------------------------------------------------------
// 1) transpose feature (B,C,N) -> fT (B,N,C)
__global__ void k_transpose(const float* __restrict__ f, float* __restrict__ fT) {
    int blk = blockIdx.x;
    int b = blk / (NN/64);
    int n0 = (blk % (NN/64)) * 64;
    __shared__ float tile[64][65];
    int t = threadIdx.x;
    int dn = t & 63, c0 = t >> 6;
    for (int i = 0; i < 16; ++i) {
        int c = c0 + i*4;
        tile[c][dn] = f[((size_t)(b*NC + c))*NN + n0 + dn];
    }
    __syncthreads();
    int o = t & 63, d0 = t >> 6;
    for (int i = 0; i < 16; ++i) {
        int dn2 = d0 + i*4;
        fT[((size_t)(b*NN + n0 + dn2))*64 + o] = tile[o][dn2];
    }
}

// ---------------------------------------------------------------------------
// 2) per-point: sim (fp64) -> fp32 softmax -> stable top-2 -> s2 index
__global__ __launch_bounds__(256) void k_s2(const float* __restrict__ fT,
                                            const int* __restrict__ knn,
                                            int* __restrict__ s2buf) {
    int p = blockIdx.x * blockDim.x + threadIdx.x;
    if (p >= NPTS) return;
    int b = p >> 15;
    const float4* cen4 = (const float4*)(fT + (size_t)p*64);
    float4 cen[16];
    #pragma unroll
    for (int q = 0; q < 16; ++q) cen[q] = cen4[q];
    float sims[16];
    #pragma unroll
    for (int k = 0; k < 16; ++k) {
        int idx = knn[(p<<4) + k];
        const float4* nb = (const float4*)(fT + ((size_t)(b*NN + idx))*64);
        double acc = 0.0;
        #pragma unroll
        for (int q = 0; q < 16; ++q) {
            float4 nv = nb[q];
            acc += (double)cen[q].x * (double)nv.x;
            acc += (double)cen[q].y * (double)nv.y;
            acc += (double)cen[q].z * (double)nv.z;
            acc += (double)cen[q].w * (double)nv.w;
        }
        sims[k] = (float)acc;
    }
    float m = sims[0];
    #pragma unroll
    for (int k = 1; k < 16; ++k) m = fmaxf(m, sims[k]);
    float e[16]; float Z = 0.f;
    #pragma unroll
    for (int k = 0; k < 16; ++k) { e[k] = expf(sims[k]-m); Z += e[k]; }
    float b1 = -1.f, b2 = -1.f; int i1 = -1, i2 = -1;
    #pragma unroll
    for (int k = 0; k < 16; ++k) {
        float a = e[k]/Z;
        if (a > b1)      { b2 = b1; i2 = i1; b1 = a; i1 = k; }
        else if (a > b2) { b2 = a; i2 = k; }
    }
    s2buf[p] = i2;
}

// ---------------------------------------------------------------------------
// 3) walk table: T[v]=s2[batch0, point v]; walkrows[v][t] = T^t(v), walkrows[v][0]=v
__global__ void k_walk(const int* __restrict__ s2buf, int* __restrict__ walkrows) {
    __shared__ int T[16];
    int t = threadIdx.x;
    if (t < 16) T[t] = s2buf[t];
    __syncthreads();
    if (t < 16) {
        int w = t;
        walkrows[t*16 + 0] = w;
        for (int s = 1; s < 16; ++s) { w = T[w]; walkrows[t*16 + s] = w; }
    }
}

// ---------------------------------------------------------------------------
// 4) per (b, s2val): window rows -> Qw,Kw,Vw ; simw stats (premax, preZ, diag)
__global__ void k_precomp(const float* __restrict__ fT,
                          const float* __restrict__ Wq, const float* __restrict__ bq,
                          const float* __restrict__ Wk, const float* __restrict__ bk,
                          const float* __restrict__ Wv, const float* __restrict__ bv,
                          const int* __restrict__ walkrows,
                          float* __restrict__ Pqw, float* __restrict__ Pkw,
                          float* __restrict__ Pvw, float* __restrict__ Pstat) {
    int blk = blockIdx.x;
    int b = blk >> 4, sv = blk & 15;
    int lane = threadIdx.x;           // 64 threads
    __shared__ float win[16][64];
    __shared__ float qw[16][65], kw[16][65];
    __shared__ float simw[16][17];
    __shared__ int wr[16];
    if (lane < 16) wr[lane] = walkrows[sv*16 + lane];
    __syncthreads();
    for (int tt = 0; tt < 16; ++tt)
        win[tt][lane] = fT[((size_t)(b*NN + wr[tt]))*64 + lane];
    __syncthreads();
    float aq[16], ak[16], av[16];
    #pragma unroll
    for (int tt = 0; tt < 16; ++tt) { aq[tt]=0.f; ak[tt]=0.f; av[tt]=0.f; }
    for (int c = 0; c < 64; ++c) {
        float wq_ = Wq[lane*64 + c], wk_ = Wk[lane*64 + c], wv_ = Wv[lane*64 + c];
        #pragma unroll
        for (int tt = 0; tt < 16; ++tt) {
            float xc = win[tt][c];
            aq[tt] = fmaf(wq_, xc, aq[tt]);
            ak[tt] = fmaf(wk_, xc, ak[tt]);
            av[tt] = fmaf(wv_, xc, av[tt]);
        }
    }
    int base = (b*16 + sv) * 16;
    #pragma unroll
    for (int tt = 0; tt < 16; ++tt) {
        float q = aq[tt] + bq[lane];
        float k = ak[tt] + bk[lane];
        float v = av[tt] + bv[lane];
        Pqw[(base+tt)*64 + lane] = q;
        Pkw[(base+tt)*64 + lane] = k;
        Pvw[(base+tt)*64 + lane] = v;
        qw[tt][lane] = q;
        kw[tt][lane] = k;
    }
    __syncthreads();
    for (int r = 0; r < 4; ++r) {
        int id = r*64 + lane;
        int i = id >> 4, j = id & 15;
        float acc = 0.f;
        for (int o = 0; o < 64; ++o) acc = fmaf(qw[i][o], kw[j][o], acc);
        simw[i][j] = acc;
    }
    __syncthreads();
    if (lane < 16) {
        int i = lane;
        float mx = simw[i][0];
        for (int j = 1; j < 16; ++j) mx = fmaxf(mx, simw[i][j]);
        float z = 0.f;
        for (int j = 0; j < 16; ++j) z += expf(simw[i][j] - mx);
        Pstat[(base+i)*3 + 0] = mx;
        Pstat[(base+i)*3 + 1] = z;
        Pstat[(base+i)*3 + 2] = simw[i][i];
    }
}

// ---------------------------------------------------------------------------
// 5) per point: center QKV matvec, diag-softmax weights, weighted V sum -> x (B,N,C)
__global__ __launch_bounds__(256) void k_attn(
        const float* __restrict__ fT,
        const float* __restrict__ Wq, const float* __restrict__ bq,
        const float* __restrict__ Wk, const float* __restrict__ bk,
        const float* __restrict__ Wv, const float* __restrict__ bv,
        const int* __restrict__ s2buf,
        const float* __restrict__ Pqw, const float* __restrict__ Pkw,
        const float* __restrict__ Pvw, const float* __restrict__ Pstat,
        float* __restrict__ x) {
    __shared__ float WTq[64*64], WTk[64*64], WTv[64*64];   // [c][o]
    __shared__ float cenL[4][64], qcl[4][64], kcl[4][64];
    __shared__ float tLs[4][16], dL[4][17];
    int t = threadIdx.x;
    for (int i = 0; i < 16; ++i) {
        int idx = t + i*256;
        int o = idx >> 6, c = idx & 63;
        WTq[c*64+o] = Wq[idx];
        WTk[c*64+o] = Wk[idx];
        WTv[c*64+o] = Wv[idx];
    }
    int wv = t >> 6, lane = t & 63;
    float bqo = bq[lane], bko = bk[lane], bvo = bv[lane];
    __syncthreads();
    int g = lane >> 4, i16 = lane & 15;
    for (int pp = 0; pp < 4; ++pp) {
        int p = (blockIdx.x * 4 + wv) * 4 + pp;
        int b = p >> 15;
        cenL[wv][lane] = fT[(size_t)p*64 + lane];
        __syncthreads();
        float q = bqo, k = bko, v = bvo;
        for (int c = 0; c < 64; ++c) {
            float xc = cenL[wv][c];
            q = fmaf(WTq[c*64+lane], xc, q);
            k = fmaf(WTk[c*64+lane], xc, k);
            v = fmaf(WTv[c*64+lane], xc, v);
        }
        qcl[wv][lane] = q;
        kcl[wv][lane] = k;
        __syncthreads();
        int sv = s2buf[p];
        int pbase = (b*16 + sv) * 16;
        float sp = 0.f, tp = 0.f;
        #pragma unroll
        for (int oo = 0; oo < 16; ++oo) {
            int o = g*16 + oo;
            sp = fmaf(Pqw[(pbase + i16)*64 + o], kcl[wv][o], sp);
            tp = fmaf(Pkw[(pbase + i16)*64 + o], qcl[wv][o], tp);
        }
        sp += __shfl_xor(sp, 16, 64); sp += __shfl_xor(sp, 32, 64);
        tp += __shfl_xor(tp, 16, 64); tp += __shfl_xor(tp, 32, 64);
        float up = q * k;
        #pragma unroll
        for (int d = 1; d < 64; d <<= 1) up += __shfl_xor(up, d, 64);
        if (g == 0) tLs[wv][i16] = tp;
        __syncthreads();
        if (g == 0) {
            float premax = Pstat[(pbase+i16)*3+0];
            float preZ   = Pstat[(pbase+i16)*3+1];
            float diag   = Pstat[(pbase+i16)*3+2];
            float mi = fmaxf(premax, sp);
            float zi = preZ * expf(premax - mi) + expf(sp - mi);
            dL[wv][i16] = expf(diag - mi) / zi;
        }
        if (lane == 16) {
            float mx = up;
            for (int j = 0; j < 16; ++j) mx = fmaxf(mx, tLs[wv][j]);
            float z = expf(up - mx);
            for (int j = 0; j < 16; ++j) z += expf(tLs[wv][j] - mx);
            dL[wv][16] = expf(up - mx) / z;
        }
        __syncthreads();
        float acc = dL[wv][16] * v;
        #pragma unroll
        for (int j = 0; j < 16; ++j)
            acc = fmaf(dL[wv][j], Pvw[(pbase+j)*64 + lane], acc);
        x[(size_t)p*64 + lane] = acc;
        __syncthreads();
    }
}

// ---------------------------------------------------------------------------
// 6) partial sums per 256-row chunk (deterministic)
__global__ void k_reduce(const float* __restrict__ x, float* __restrict__ part) {
    int r = blockIdx.x, c = threadIdx.x;   // 256 blocks x 64 threads
    size_t base = (size_t)r * 256 * 64;
    float s = 0.f, sq = 0.f;
    for (int row = 0; row < 256; ++row) {
        float vv = x[base + row*64 + c];
        s += vv; sq = fmaf(vv, vv, sq);
    }
    part[r*64 + c] = s;
    part[256*64 + r*64 + c] = sq;
}

// 7) finalize mean/var per channel
__global__ void k_stats(const float* __restrict__ part, float* __restrict__ mv) {
    int c = threadIdx.x;   // 64
    float s = 0.f, sq = 0.f;
    for (int r = 0; r < 256; ++r) {
        s  += part[r*64+c];
        sq += part[256*64 + r*64+c];
    }
    float mean = s / (float)NPTS;
    float var  = sq / (float)NPTS - mean*mean;
    mv[c] = mean; mv[64+c] = var;
}

// ---------------------------------------------------------------------------
// 8) normalize + relu + residual; update fT in place; write out slice (B,C,N)
__global__ void k_norm(const float* __restrict__ x, float* __restrict__ fT,
                       const float* __restrict__ mv,
                       const float* __restrict__ gamma, const float* __restrict__ beta,
                       float* __restrict__ out, int l) {
    int blk = blockIdx.x;
    int b = blk / (NN/64);
    int n0 = (blk % (NN/64)) * 64;
    __shared__ float tile[64][65];   // [dn][c]
    int t = threadIdx.x;
    int c = t & 63, d0 = t >> 6;
    float mean = mv[c], var = mv[64+c];
    float inv = 1.0f / sqrtf(var + 1e-5f);
    float ga = gamma[c], be = beta[c];
    for (int i = 0; i < 16; ++i) {
        int dn = d0 + i*4;
        size_t pi = ((size_t)(b*NN + n0 + dn))*64 + c;
        float y = fT[pi] + fmaxf(ga * (x[pi] - mean) * inv + be, 0.f);
        fT[pi] = y;
        tile[dn][c] = y;
    }
    __syncthreads();
    int dn2 = t & 63, c0 = t >> 6;
    for (int i = 0; i < 16; ++i) {
        int cc = c0 + i*4;
        out[((size_t)(b*192 + l*64 + cc))*NN + n0 + dn2] = tile[dn2][cc];
    }
}

// ---------------------------------------------------------------------------
extern "C" void kernel_launch(void* const* d_in, const int* in_sizes, int n_in,
                              void* d_out, int out_size, void* d_ws, size_t ws_size,
                              hipStream_t stream) {
    const float* feature = (const float*)d_in[0];
    const int*   knn     = (const int*)d_in[1];
    const float* Wq = (const float*)d_in[2];
    const float* bq = (const float*)d_in[3];
    const float* Wk = (const float*)d_in[4];
    const float* bk = (const float*)d_in[5];
    const float* Wv = (const float*)d_in[6];
    const float* bv = (const float*)d_in[7];
    const float* gamma = (const float*)d_in[8];
    const float* beta  = (const float*)d_in[9];
    float* out = (float*)d_out;

    char* ws = (char*)d_ws;
    float* fT       = (float*)ws;                                  // 16,777,216 B
    float* x        = (float*)(ws + 16777216);                     // 16,777,216 B
    int*   s2buf    = (int*)  (ws + 2*16777216);                   // 262,144 B
    int*   walkrows = (int*)  (ws + 2*16777216 + 262144);          // 1,024 B
    float* Pqw      = (float*)(ws + 2*16777216 + 262144 + 1024);
    float* Pkw   = Pqw + 2*16*16*64;
    float* Pvw   = Pkw + 2*16*16*64;
    float* Pstat = Pvw + 2*16*16*64;        // 2*16*16*3
    float* part  = Pstat + 2*16*16*3;       // 2*256*64
    float* mv    = part + 2*256*64;         // 128

    k_transpose<<<NB*(NN/64), 256, 0, stream>>>(feature, fT);
    k_s2<<<NPTS/256, 256, 0, stream>>>(fT, knn, s2buf);
    k_walk<<<1, 64, 0, stream>>>(s2buf, walkrows);
    for (int l = 0; l < 3; ++l) {
        k_precomp<<<32, 64, 0, stream>>>(fT, Wq + l*4096, bq + l*64,
                                         Wk + l*4096, bk + l*64,
                                         Wv + l*4096, bv + l*64,
                                         walkrows, Pqw, Pkw, Pvw, Pstat);
        k_attn<<<NPTS/16, 256, 0, stream>>>(fT, Wq + l*4096, bq + l*64,
                                            Wk + l*4096, bk + l*64,
                                            Wv + l*4096, bv + l*64,
                                            s2buf, Pqw, Pkw, Pvw, Pstat, x);
        k_reduce<<<256, 64, 0, stream>>>(x, part);
        k_stats<<<1, 64, 0, stream>>>(part, mv);
        k_norm<<<NB*(NN/64), 256, 0, stream>>>(x, fT, mv, gamma + l*64, beta + l*64, out, l);
    }
}

// Round 2
// 671.836 us; speedup vs baseline: 1.5370x; 1.5370x over previous
//
#include <hip/hip_runtime.h>
#include <math.h>

#define NB 2
#define NC 64
#define NN 32768
#define NK 16
#define NPTS (NB*NN)   // 65536

// ---------------------------------------------------------------------------
// 1) transpose feature (B,C,N) -> fT (B,N,C)
__global__ void k_transpose(const float* __restrict__ f, float* __restrict__ fT) {
    int blk = blockIdx.x;
    int b = blk / (NN/64);
    int n0 = (blk % (NN/64)) * 64;
    __shared__ float tile[64][65];
    int t = threadIdx.x;
    int dn = t & 63, c0 = t >> 6;
    for (int i = 0; i < 16; ++i) {
        int c = c0 + i*4;
        tile[c][dn] = f[((size_t)(b*NC + c))*NN + n0 + dn];
    }
    __syncthreads();
    int o = t & 63, d0 = t >> 6;
    for (int i = 0; i < 16; ++i) {
        int dn2 = d0 + i*4;
        fT[((size_t)(b*NN + n0 + dn2))*64 + o] = tile[o][dn2];
    }
}

// ---------------------------------------------------------------------------
// 2) per-point: sim (fp64) -> fp32 softmax -> stable top-2 -> s2 index
__global__ __launch_bounds__(256) void k_s2(const float* __restrict__ fT,
                                            const int* __restrict__ knn,
                                            int* __restrict__ s2buf) {
    int p = blockIdx.x * blockDim.x + threadIdx.x;
    if (p >= NPTS) return;
    int b = p >> 15;
    const float4* cen4 = (const float4*)(fT + (size_t)p*64);
    float4 cen[16];
    #pragma unroll
    for (int q = 0; q < 16; ++q) cen[q] = cen4[q];
    float sims[16];
    #pragma unroll
    for (int k = 0; k < 16; ++k) {
        int idx = knn[(p<<4) + k];
        const float4* nb = (const float4*)(fT + ((size_t)(b*NN + idx))*64);
        double acc = 0.0;
        #pragma unroll
        for (int q = 0; q < 16; ++q) {
            float4 nv = nb[q];
            acc += (double)cen[q].x * (double)nv.x;
            acc += (double)cen[q].y * (double)nv.y;
            acc += (double)cen[q].z * (double)nv.z;
            acc += (double)cen[q].w * (double)nv.w;
        }
        sims[k] = (float)acc;
    }
    float m = sims[0];
    #pragma unroll
    for (int k = 1; k < 16; ++k) m = fmaxf(m, sims[k]);
    float e[16]; float Z = 0.f;
    #pragma unroll
    for (int k = 0; k < 16; ++k) { e[k] = expf(sims[k]-m); Z += e[k]; }
    float b1 = -1.f, b2 = -1.f; int i1 = -1, i2 = -1;
    #pragma unroll
    for (int k = 0; k < 16; ++k) {
        float a = e[k]/Z;
        if (a > b1)      { b2 = b1; i2 = i1; b1 = a; i1 = k; }
        else if (a > b2) { b2 = a; i2 = k; }
    }
    s2buf[p] = i2;
}

// ---------------------------------------------------------------------------
// 3) walk table
__global__ void k_walk(const int* __restrict__ s2buf, int* __restrict__ walkrows) {
    __shared__ int T[16];
    int t = threadIdx.x;
    if (t < 16) T[t] = s2buf[t];
    __syncthreads();
    if (t < 16) {
        int w = t;
        walkrows[t*16 + 0] = w;
        for (int s = 1; s < 16; ++s) { w = T[w]; walkrows[t*16 + s] = w; }
    }
}

// ---------------------------------------------------------------------------
// 4) per (b, s2val): window rows -> Qw,Kw,Vw ; simw stats (premax, preZ, diag)
__global__ void k_precomp(const float* __restrict__ fT,
                          const float* __restrict__ Wq, const float* __restrict__ bq,
                          const float* __restrict__ Wk, const float* __restrict__ bk,
                          const float* __restrict__ Wv, const float* __restrict__ bv,
                          const int* __restrict__ walkrows,
                          float* __restrict__ Pqw, float* __restrict__ Pkw,
                          float* __restrict__ Pvw, float* __restrict__ Pstat) {
    int blk = blockIdx.x;
    int b = blk >> 4, sv = blk & 15;
    int lane = threadIdx.x;           // 64 threads
    __shared__ float win[16][64];
    __shared__ float qw[16][65], kw[16][65];
    __shared__ float simw[16][17];
    __shared__ int wr[16];
    if (lane < 16) wr[lane] = walkrows[sv*16 + lane];
    __syncthreads();
    for (int tt = 0; tt < 16; ++tt)
        win[tt][lane] = fT[((size_t)(b*NN + wr[tt]))*64 + lane];
    __syncthreads();
    float aq[16], ak[16], av[16];
    #pragma unroll
    for (int tt = 0; tt < 16; ++tt) { aq[tt]=0.f; ak[tt]=0.f; av[tt]=0.f; }
    for (int c = 0; c < 64; ++c) {
        float wq_ = Wq[lane*64 + c], wk_ = Wk[lane*64 + c], wv_ = Wv[lane*64 + c];
        #pragma unroll
        for (int tt = 0; tt < 16; ++tt) {
            float xc = win[tt][c];
            aq[tt] = fmaf(wq_, xc, aq[tt]);
            ak[tt] = fmaf(wk_, xc, ak[tt]);
            av[tt] = fmaf(wv_, xc, av[tt]);
        }
    }
    int base = (b*16 + sv) * 16;
    #pragma unroll
    for (int tt = 0; tt < 16; ++tt) {
        float q = aq[tt] + bq[lane];
        float k = ak[tt] + bk[lane];
        float v = av[tt] + bv[lane];
        Pqw[(base+tt)*64 + lane] = q;
        Pkw[(base+tt)*64 + lane] = k;
        Pvw[(base+tt)*64 + lane] = v;
        qw[tt][lane] = q;
        kw[tt][lane] = k;
    }
    __syncthreads();
    for (int r = 0; r < 4; ++r) {
        int id = r*64 + lane;
        int i = id >> 4, j = id & 15;
        float acc = 0.f;
        for (int o = 0; o < 64; ++o) acc = fmaf(qw[i][o], kw[j][o], acc);
        simw[i][j] = acc;
    }
    __syncthreads();
    if (lane < 16) {
        int i = lane;
        float mx = simw[i][0];
        for (int j = 1; j < 16; ++j) mx = fmaxf(mx, simw[i][j]);
        float z = 0.f;
        for (int j = 0; j < 16; ++j) z += expf(simw[i][j] - mx);
        Pstat[(base+i)*3 + 0] = mx;
        Pstat[(base+i)*3 + 1] = z;
        Pstat[(base+i)*3 + 2] = simw[i][i];
    }
}

// ---------------------------------------------------------------------------
// 5) QKV GEMM: for a chunk of points, compute qc,kc,vc = fT @ W^T + b.
//    Tile: 128 points x 64 outputs, one weight matrix per blockIdx.y.
//    Thread: (pp = t>>2 in 0..63, q4 = t&3) -> points {pp, pp+64}, outputs q4*16..+15.
//    Ws row layout: 4 chunks of 16 floats at offsets q*20 (row stride 84)
//    -> the 4 chunk starts hit banks {0,20,8,28}+4k: disjoint -> conflict-free b128.
__global__ __launch_bounds__(256, 2) void k_qkv(
        const float* __restrict__ fT, int p0,
        const float* __restrict__ Wq, const float* __restrict__ bq,
        const float* __restrict__ Wk, const float* __restrict__ bk,
        const float* __restrict__ Wv, const float* __restrict__ bv,
        float* __restrict__ qc, float* __restrict__ kc, float* __restrict__ vc) {
    int arr = blockIdx.y;
    const float* W  = arr == 0 ? Wq : (arr == 1 ? Wk : Wv);
    const float* bb = arr == 0 ? bq : (arr == 1 ? bk : bv);
    float* outp     = arr == 0 ? qc : (arr == 1 ? kc : vc);

    __shared__ float Xs[128*65];
    __shared__ float Ws[64*84];
    __shared__ float bs[64];
    int t = threadIdx.x;
    size_t gbase = ((size_t)p0 + (size_t)blockIdx.x*128) * 64;
    #pragma unroll
    for (int i = 0; i < 32; ++i) {
        int idx = t + i*256;
        int p = idx >> 6, c = idx & 63;
        Xs[p*65 + c] = fT[gbase + idx];
    }
    #pragma unroll
    for (int i = 0; i < 16; ++i) {
        int idx = t + i*256;
        int o = idx >> 6, c = idx & 63;
        Ws[c*84 + (o >> 4)*20 + (o & 15)] = W[idx];
    }
    if (t < 64) bs[t] = bb[t];
    __syncthreads();

    int pp = t >> 2, q4 = t & 3;
    float accA[16], accB[16];
    #pragma unroll
    for (int i = 0; i < 16; ++i) { accA[i] = 0.f; accB[i] = 0.f; }
    #pragma unroll 4
    for (int k = 0; k < 64; ++k) {
        float xa = Xs[pp*65 + k];
        float xb = Xs[(pp+64)*65 + k];
        const float* wr = &Ws[k*84 + q4*20];
        float4 w0 = *(const float4*)(wr + 0);
        float4 w1 = *(const float4*)(wr + 4);
        float4 w2 = *(const float4*)(wr + 8);
        float4 w3 = *(const float4*)(wr + 12);
        accA[0]  = fmaf(xa, w0.x, accA[0]);  accB[0]  = fmaf(xb, w0.x, accB[0]);
        accA[1]  = fmaf(xa, w0.y, accA[1]);  accB[1]  = fmaf(xb, w0.y, accB[1]);
        accA[2]  = fmaf(xa, w0.z, accA[2]);  accB[2]  = fmaf(xb, w0.z, accB[2]);
        accA[3]  = fmaf(xa, w0.w, accA[3]);  accB[3]  = fmaf(xb, w0.w, accB[3]);
        accA[4]  = fmaf(xa, w1.x, accA[4]);  accB[4]  = fmaf(xb, w1.x, accB[4]);
        accA[5]  = fmaf(xa, w1.y, accA[5]);  accB[5]  = fmaf(xb, w1.y, accB[5]);
        accA[6]  = fmaf(xa, w1.z, accA[6]);  accB[6]  = fmaf(xb, w1.z, accB[6]);
        accA[7]  = fmaf(xa, w1.w, accA[7]);  accB[7]  = fmaf(xb, w1.w, accB[7]);
        accA[8]  = fmaf(xa, w2.x, accA[8]);  accB[8]  = fmaf(xb, w2.x, accB[8]);
        accA[9]  = fmaf(xa, w2.y, accA[9]);  accB[9]  = fmaf(xb, w2.y, accB[9]);
        accA[10] = fmaf(xa, w2.z, accA[10]); accB[10] = fmaf(xb, w2.z, accB[10]);
        accA[11] = fmaf(xa, w2.w, accA[11]); accB[11] = fmaf(xb, w2.w, accB[11]);
        accA[12] = fmaf(xa, w3.x, accA[12]); accB[12] = fmaf(xb, w3.x, accB[12]);
        accA[13] = fmaf(xa, w3.y, accA[13]); accB[13] = fmaf(xb, w3.y, accB[13]);
        accA[14] = fmaf(xa, w3.z, accA[14]); accB[14] = fmaf(xb, w3.z, accB[14]);
        accA[15] = fmaf(xa, w3.w, accA[15]); accB[15] = fmaf(xb, w3.w, accB[15]);
    }
    size_t rowA = ((size_t)blockIdx.x*128 + pp) * 64 + q4*16;
    size_t rowB = rowA + (size_t)64*64;
    #pragma unroll
    for (int g4 = 0; g4 < 4; ++g4) {
        float4 va, vb;
        float b0 = bs[q4*16 + g4*4 + 0], b1 = bs[q4*16 + g4*4 + 1];
        float b2 = bs[q4*16 + g4*4 + 2], b3 = bs[q4*16 + g4*4 + 3];
        va.x = accA[g4*4+0] + b0; va.y = accA[g4*4+1] + b1;
        va.z = accA[g4*4+2] + b2; va.w = accA[g4*4+3] + b3;
        vb.x = accB[g4*4+0] + b0; vb.y = accB[g4*4+1] + b1;
        vb.z = accB[g4*4+2] + b2; vb.w = accB[g4*4+3] + b3;
        *(float4*)&outp[rowA + g4*4] = va;
        *(float4*)&outp[rowB + g4*4] = vb;
    }
}

// ---------------------------------------------------------------------------
// 6) combine: per point, diag-softmax weights + weighted V sum -> x (B,N,C).
//    Wave-parallel, no LDS, no barriers: all cross-lane via shuffles.
//    lane = (g = lane>>4 channel-quarter, i16 = lane&15 window row).
__global__ __launch_bounds__(256) void k_comb(
        const float* __restrict__ qc, const float* __restrict__ kc,
        const float* __restrict__ vc, const int* __restrict__ s2buf,
        const float* __restrict__ Pqw, const float* __restrict__ Pkw,
        const float* __restrict__ Pvw, const float* __restrict__ Pstat,
        float* __restrict__ x, int p0) {
    int t = threadIdx.x;
    int wv = t >> 6, lane = t & 63;
    int g = lane >> 4, i16 = lane & 15;
    #pragma unroll
    for (int pp = 0; pp < 4; ++pp) {
        int pl = blockIdx.x*16 + wv*4 + pp;   // chunk-local point
        int p  = p0 + pl;                      // global point
        int b  = p >> 15;
        int sv = s2buf[p];
        int pbase = (b*16 + sv) * 16;
        const float* qrow = qc + (size_t)pl*64;
        const float* krow = kc + (size_t)pl*64;
        float sp = 0.f, tp = 0.f, upp = 0.f;
        #pragma unroll
        for (int j = 0; j < 4; ++j) {
            float4 pq = *(const float4*)&Pqw[(pbase+i16)*64 + g*16 + j*4];
            float4 pk = *(const float4*)&Pkw[(pbase+i16)*64 + g*16 + j*4];
            float4 kk = *(const float4*)&krow[g*16 + j*4];
            float4 qq = *(const float4*)&qrow[g*16 + j*4];
            sp  = fmaf(pq.x,kk.x, fmaf(pq.y,kk.y, fmaf(pq.z,kk.z, fmaf(pq.w,kk.w, sp))));
            tp  = fmaf(pk.x,qq.x, fmaf(pk.y,qq.y, fmaf(pk.z,qq.z, fmaf(pk.w,qq.w, tp))));
            upp = fmaf(qq.x,kk.x, fmaf(qq.y,kk.y, fmaf(qq.z,kk.z, fmaf(qq.w,kk.w, upp))));
        }
        sp  += __shfl_xor(sp, 16, 64);  sp  += __shfl_xor(sp, 32, 64);
        tp  += __shfl_xor(tp, 16, 64);  tp  += __shfl_xor(tp, 32, 64);
        upp += __shfl_xor(upp, 16, 64); upp += __shfl_xor(upp, 32, 64);
        // row weight for row i16 (every lane computes its row's weight)
        float premax = Pstat[(pbase+i16)*3 + 0];
        float preZ   = Pstat[(pbase+i16)*3 + 1];
        float diag   = Pstat[(pbase+i16)*3 + 2];
        float mi = fmaxf(premax, sp);
        float zi = preZ * expf(premax - mi) + expf(sp - mi);
        float dLrow = expf(diag - mi) / zi;
        // center weight (identical on all lanes)
        float mxt = tp;
        mxt = fmaxf(mxt, __shfl_xor(mxt, 1, 64));
        mxt = fmaxf(mxt, __shfl_xor(mxt, 2, 64));
        mxt = fmaxf(mxt, __shfl_xor(mxt, 4, 64));
        mxt = fmaxf(mxt, __shfl_xor(mxt, 8, 64));
        float mc = fmaxf(upp, mxt);
        float ze = expf(tp - mc);
        ze += __shfl_xor(ze, 1, 64);
        ze += __shfl_xor(ze, 2, 64);
        ze += __shfl_xor(ze, 4, 64);
        ze += __shfl_xor(ze, 8, 64);
        float ec = expf(upp - mc);
        float dcen = ec / (ze + ec);
        // weighted V sum: lane = output channel
        float acc = dcen * vc[(size_t)pl*64 + lane];
        #pragma unroll
        for (int j = 0; j < 16; ++j) {
            float wj = __shfl(dLrow, j, 64);
            acc = fmaf(wj, Pvw[(pbase+j)*64 + lane], acc);
        }
        x[(size_t)p*64 + lane] = acc;
    }
}

// ---------------------------------------------------------------------------
// 7) partial sums per 256-row chunk (deterministic)
__global__ void k_reduce(const float* __restrict__ x, float* __restrict__ part) {
    int r = blockIdx.x, c = threadIdx.x;   // 256 blocks x 64 threads
    size_t base = (size_t)r * 256 * 64;
    float s = 0.f, sq = 0.f;
    for (int row = 0; row < 256; ++row) {
        float vv = x[base + row*64 + c];
        s += vv; sq = fmaf(vv, vv, sq);
    }
    part[r*64 + c] = s;
    part[256*64 + r*64 + c] = sq;
}

// 8) finalize mean/var per channel
__global__ void k_stats(const float* __restrict__ part, float* __restrict__ mv) {
    int c = threadIdx.x;   // 64
    float s = 0.f, sq = 0.f;
    for (int r = 0; r < 256; ++r) {
        s  += part[r*64+c];
        sq += part[256*64 + r*64+c];
    }
    float mean = s / (float)NPTS;
    float var  = sq / (float)NPTS - mean*mean;
    mv[c] = mean; mv[64+c] = var;
}

// ---------------------------------------------------------------------------
// 9) normalize + relu + residual; update fT in place; write out slice (B,C,N)
__global__ void k_norm(const float* __restrict__ x, float* __restrict__ fT,
                       const float* __restrict__ mv,
                       const float* __restrict__ gamma, const float* __restrict__ beta,
                       float* __restrict__ out, int l) {
    int blk = blockIdx.x;
    int b = blk / (NN/64);
    int n0 = (blk % (NN/64)) * 64;
    __shared__ float tile[64][65];   // [dn][c]
    int t = threadIdx.x;
    int c = t & 63, d0 = t >> 6;
    float mean = mv[c], var = mv[64+c];
    float inv = 1.0f / sqrtf(var + 1e-5f);
    float ga = gamma[c], be = beta[c];
    for (int i = 0; i < 16; ++i) {
        int dn = d0 + i*4;
        size_t pi = ((size_t)(b*NN + n0 + dn))*64 + c;
        float y = fT[pi] + fmaxf(ga * (x[pi] - mean) * inv + be, 0.f);
        fT[pi] = y;
        tile[dn][c] = y;
    }
    __syncthreads();
    int dn2 = t & 63, c0 = t >> 6;
    for (int i = 0; i < 16; ++i) {
        int cc = c0 + i*4;
        out[((size_t)(b*192 + l*64 + cc))*NN + n0 + dn2] = tile[dn2][cc];
    }
}

// ---------------------------------------------------------------------------
extern "C" void kernel_launch(void* const* d_in, const int* in_sizes, int n_in,
                              void* d_out, int out_size, void* d_ws, size_t ws_size,
                              hipStream_t stream) {
    const float* feature = (const float*)d_in[0];
    const int*   knn     = (const int*)d_in[1];
    const float* Wq = (const float*)d_in[2];
    const float* bq = (const float*)d_in[3];
    const float* Wk = (const float*)d_in[4];
    const float* bk = (const float*)d_in[5];
    const float* Wv = (const float*)d_in[6];
    const float* bv = (const float*)d_in[7];
    const float* gamma = (const float*)d_in[8];
    const float* beta  = (const float*)d_in[9];
    float* out = (float*)d_out;

    char* ws = (char*)d_ws;
    float* fT       = (float*)ws;                         // 16,777,216 B
    float* x        = (float*)(ws + 16777216);            // 16,777,216 B
    int*   s2buf    = (int*)  (ws + 33554432);            //    262,144 B
    int*   walkrows = (int*)  (ws + 33816576);            //      1,024 B
    float* Pqw      = (float*)(ws + 33817600);            //    262,144 B
    float* Pkw      = (float*)(ws + 34079744);            //    262,144 B
    float* Pvw      = (float*)(ws + 34341888);            //    262,144 B
    float* Pstat    = (float*)(ws + 34604032);            //      6,144 B
    float* part     = (float*)(ws + 34610176);            //    131,072 B
    float* mv       = (float*)(ws + 34741248);            //        512 B
    size_t qkv_off  = 34741760;

    // chunked qc/kc/vc sized from available workspace (768 B per point total)
    size_t avail = (ws_size > qkv_off) ? (ws_size - qkv_off) : 0;
    size_t chunk = avail / 768;
    chunk = (chunk / 2048) * 2048;
    if (chunk > (size_t)NPTS) chunk = NPTS;
    if (chunk < 2048) chunk = 2048;   // minimum footprint (baseline ws was larger)
    float* qc = (float*)(ws + qkv_off);
    float* kc = qc + chunk*64;
    float* vc = kc + chunk*64;

    k_transpose<<<NB*(NN/64), 256, 0, stream>>>(feature, fT);
    k_s2<<<NPTS/256, 256, 0, stream>>>(fT, knn, s2buf);
    k_walk<<<1, 64, 0, stream>>>(s2buf, walkrows);
    for (int l = 0; l < 3; ++l) {
        k_precomp<<<32, 64, 0, stream>>>(fT, Wq + l*4096, bq + l*64,
                                         Wk + l*4096, bk + l*64,
                                         Wv + l*4096, bv + l*64,
                                         walkrows, Pqw, Pkw, Pvw, Pstat);
        for (size_t p0 = 0; p0 < NPTS; p0 += chunk) {
            size_t cn = (p0 + chunk <= NPTS) ? chunk : (NPTS - p0);
            dim3 gq((unsigned)(cn/128), 3);
            k_qkv<<<gq, 256, 0, stream>>>(fT, (int)p0,
                                          Wq + l*4096, bq + l*64,
                                          Wk + l*4096, bk + l*64,
                                          Wv + l*4096, bv + l*64,
                                          qc, kc, vc);
            k_comb<<<(unsigned)(cn/16), 256, 0, stream>>>(qc, kc, vc, s2buf,
                                                          Pqw, Pkw, Pvw, Pstat,
                                                          x, (int)p0);
        }
        k_reduce<<<256, 64, 0, stream>>>(x, part);
        k_stats<<<1, 64, 0, stream>>>(part, mv);
        k_norm<<<NB*(NN/64), 256, 0, stream>>>(x, fT, mv, gamma + l*64, beta + l*64, out, l);
    }
}

// Round 3
// 526.277 us; speedup vs baseline: 1.9621x; 1.2766x over previous
//
#include <hip/hip_runtime.h>
#include <math.h>

#define NB 2
#define NC 64
#define NN 32768
#define NPTS (NB*NN)   // 65536
#define NWAVES 1056
#define NSLOTS 67584

// ---------------------------------------------------------------------------
// 1) transpose feature (B,C,N) -> fT (B,N,C)
__global__ void k_transpose(const float* __restrict__ f, float* __restrict__ fT) {
    int blk = blockIdx.x;
    int b = blk / (NN/64);
    int n0 = (blk % (NN/64)) * 64;
    __shared__ float tile[64][65];
    int t = threadIdx.x;
    int dn = t & 63, c0 = t >> 6;
    for (int i = 0; i < 16; ++i) {
        int c = c0 + i*4;
        tile[c][dn] = f[((size_t)(b*NC + c))*NN + n0 + dn];
    }
    __syncthreads();
    int o = t & 63, d0 = t >> 6;
    for (int i = 0; i < 16; ++i) {
        int dn2 = d0 + i*4;
        fT[((size_t)(b*NN + n0 + dn2))*64 + o] = tile[o][dn2];
    }
}

// ---------------------------------------------------------------------------
// 2) per-point top-2: 4 lanes per point, fp64 dot, shfl reduce.
__global__ __launch_bounds__(256, 4) void k_s2(const float* __restrict__ fT,
                                               const int* __restrict__ knn,
                                               int* __restrict__ s2buf) {
    int t = threadIdx.x;
    int gp = blockIdx.x * 64 + (t >> 2);
    int q4 = t & 3;
    int b = gp >> 15;
    const float4* cen4 = (const float4*)(fT + (size_t)gp*64 + q4*16);
    float4 c0 = cen4[0], c1 = cen4[1], c2 = cen4[2], c3 = cen4[3];
    float sims[16];
    #pragma unroll
    for (int k = 0; k < 16; ++k) {
        int idx = knn[(gp << 4) + k];
        const float4* nb = (const float4*)(fT + ((size_t)(b*NN + idx))*64 + q4*16);
        float4 n0 = nb[0], n1 = nb[1], n2 = nb[2], n3 = nb[3];
        double a = 0.0;
        a += (double)c0.x*(double)n0.x + (double)c0.y*(double)n0.y
           + (double)c0.z*(double)n0.z + (double)c0.w*(double)n0.w;
        a += (double)c1.x*(double)n1.x + (double)c1.y*(double)n1.y
           + (double)c1.z*(double)n1.z + (double)c1.w*(double)n1.w;
        a += (double)c2.x*(double)n2.x + (double)c2.y*(double)n2.y
           + (double)c2.z*(double)n2.z + (double)c2.w*(double)n2.w;
        a += (double)c3.x*(double)n3.x + (double)c3.y*(double)n3.y
           + (double)c3.z*(double)n3.z + (double)c3.w*(double)n3.w;
        a += __shfl_xor(a, 1, 64);
        a += __shfl_xor(a, 2, 64);
        sims[k] = (float)a;
    }
    float m = sims[0];
    #pragma unroll
    for (int k = 1; k < 16; ++k) m = fmaxf(m, sims[k]);
    float e[16]; float Z = 0.f;
    #pragma unroll
    for (int k = 0; k < 16; ++k) { e[k] = expf(sims[k]-m); Z += e[k]; }
    float b1 = -1.f, b2 = -1.f; int i1 = -1, i2 = -1;
    #pragma unroll
    for (int k = 0; k < 16; ++k) {
        float a = e[k]/Z;
        if (a > b1)      { b2 = b1; i2 = i1; b1 = a; i1 = k; }
        else if (a > b2) { b2 = a; i2 = k; }
    }
    if (q4 == 0) s2buf[gp] = i2;
}

// ---------------------------------------------------------------------------
// 3) walk table
__global__ void k_walk(const int* __restrict__ s2buf, int* __restrict__ walkrows) {
    __shared__ int T[16];
    int t = threadIdx.x;
    if (t < 16) T[t] = s2buf[t];
    __syncthreads();
    if (t < 16) {
        int w = t;
        walkrows[t*16 + 0] = w;
        for (int s = 1; s < 16; ++s) { w = T[w]; walkrows[t*16 + s] = w; }
    }
}

// ---------------------------------------------------------------------------
// bucketing: counting sort of points by (b, sv) into wave-aligned slot lists
__global__ void k_init(int* __restrict__ slotlist, int* __restrict__ wavebucket,
                       int* __restrict__ hist, int* __restrict__ head) {
    int idx = blockIdx.x*256 + threadIdx.x;
    if (idx < NSLOTS) slotlist[idx] = -1;
    if (idx < NWAVES) wavebucket[idx] = -1;
    if (idx < 32) { hist[idx] = 0; head[idx] = 0; }
}

__global__ void k_hist(const int* __restrict__ s2buf, int* __restrict__ hist) {
    __shared__ int h[32];
    int t = threadIdx.x;
    if (t < 32) h[t] = 0;
    __syncthreads();
    int p = blockIdx.x*256 + t;
    int bucket = (p >> 15)*16 + s2buf[p];
    atomicAdd(&h[bucket], 1);
    __syncthreads();
    if (t < 32 && h[t]) atomicAdd(&hist[t], h[t]);
}

__global__ void k_offsets(const int* __restrict__ hist, int* __restrict__ head,
                          int* __restrict__ wavebucket) {
    int off = 0;
    for (int i = 0; i < 32; ++i) {
        head[i] = off;
        int nw = (hist[i] + 63) >> 6;
        int w0 = off >> 6;
        for (int w = 0; w < nw; ++w) wavebucket[w0 + w] = i;
        off += nw << 6;
    }
}

__global__ void k_scatter(const int* __restrict__ s2buf, int* __restrict__ head,
                          int* __restrict__ slotlist) {
    int p = blockIdx.x*256 + threadIdx.x;
    int bucket = (p >> 15)*16 + s2buf[p];
    int slot = atomicAdd(&head[bucket], 1);
    slotlist[slot] = p;
}

// ---------------------------------------------------------------------------
// 4) per (b, sv): window QKV + transposed tables + softmax stats
__global__ __launch_bounds__(256) void k_precomp(
        const float* __restrict__ fT,
        const float* __restrict__ Wq, const float* __restrict__ bq,
        const float* __restrict__ Wk, const float* __restrict__ bk,
        const float* __restrict__ Wv, const float* __restrict__ bv,
        const int* __restrict__ walkrows,
        float* __restrict__ PqwT, float* __restrict__ PkwT,
        float* __restrict__ PvwT, float* __restrict__ Pstat) {
    int blk = blockIdx.x;
    int b = blk >> 4, sv = blk & 15;
    int bsvb = (b*16 + sv)*1024, bs48 = (b*16 + sv)*48;
    __shared__ float win[16][64];
    __shared__ float Wl[64][65];
    __shared__ float qw[16][65], kw[16][65];
    __shared__ float simw[16][17];
    __shared__ int wr[16];
    int t = threadIdx.x;
    if (t < 16) wr[t] = walkrows[sv*16 + t];
    __syncthreads();
    #pragma unroll
    for (int i = 0; i < 4; ++i) {
        int idx = t + i*256; int tt = idx >> 6, c = idx & 63;
        win[tt][c] = fT[((size_t)(b*NN + wr[tt]))*64 + c];
    }
    int wv = t >> 6, lane = t & 63;
    for (int m = 0; m < 3; ++m) {
        const float* W  = m == 0 ? Wq : (m == 1 ? Wk : Wv);
        const float* bb = m == 0 ? bq : (m == 1 ? bk : bv);
        __syncthreads();
        #pragma unroll
        for (int i = 0; i < 16; ++i) {
            int idx = t + i*256;
            Wl[idx >> 6][idx & 63] = W[idx];
        }
        __syncthreads();
        float acc[4] = {0.f, 0.f, 0.f, 0.f};
        for (int c = 0; c < 64; ++c) {
            float w_ = Wl[lane][c];
            #pragma unroll
            for (int r = 0; r < 4; ++r) acc[r] = fmaf(w_, win[wv*4 + r][c], acc[r]);
        }
        float bias = bb[lane];
        #pragma unroll
        for (int r = 0; r < 4; ++r) {
            int tt = wv*4 + r;
            float val = acc[r] + bias;
            if (m == 0)      { qw[tt][lane] = val; PqwT[bsvb + lane*16 + tt] = val; }
            else if (m == 1) { kw[tt][lane] = val; PkwT[bsvb + lane*16 + tt] = val; }
            else             {                     PvwT[bsvb + lane*16 + tt] = val; }
        }
    }
    __syncthreads();
    {
        int i = t >> 4, j = t & 15;
        float acc = 0.f;
        for (int o = 0; o < 64; ++o) acc = fmaf(qw[i][o], kw[j][o], acc);
        simw[i][j] = acc;
    }
    __syncthreads();
    if (t < 16) {
        float mx = simw[t][0];
        for (int j = 1; j < 16; ++j) mx = fmaxf(mx, simw[t][j]);
        float z = 0.f;
        for (int j = 0; j < 16; ++j) z += expf(simw[t][j] - mx);
        Pstat[bs48 + t*3 + 0] = mx;
        Pstat[bs48 + t*3 + 1] = z;
        Pstat[bs48 + t*3 + 2] = simw[t][t];
    }
}

// ---------------------------------------------------------------------------
// 5) fused per-layer point kernel: lane = point, bucket-uniform scalar tables.
__global__ __launch_bounds__(256) void k_layer(
        const float* __restrict__ fT,
        const float* __restrict__ Wq, const float* __restrict__ bq,
        const float* __restrict__ Wk, const float* __restrict__ bk,
        const float* __restrict__ Wv, const float* __restrict__ bv,
        const float* __restrict__ PqwT, const float* __restrict__ PkwT,
        const float* __restrict__ PvwT, const float* __restrict__ Pstat,
        const int* __restrict__ slotlist, const int* __restrict__ wavebucket,
        float* __restrict__ x) {
    int t = threadIdx.x, wv = t >> 6, lane = t & 63;
    int w = blockIdx.x*4 + wv;
    int bucket = wavebucket[w];
    if (bucket < 0) return;
    int bsvb = bucket*1024, bs48 = bucket*48;
    int pid = slotlist[(w << 6) + lane];
    int p = pid < 0 ? 0 : pid;

    float xr[64];
    {
        const float4* xp = (const float4*)(fT + (size_t)p*64);
        #pragma unroll
        for (int i = 0; i < 16; ++i) {
            float4 v4 = xp[i];
            xr[i*4+0] = v4.x; xr[i*4+1] = v4.y; xr[i*4+2] = v4.z; xr[i*4+3] = v4.w;
        }
    }
    float sp[16], tp[16];
    #pragma unroll
    for (int i = 0; i < 16; ++i) { sp[i] = 0.f; tp[i] = 0.f; }
    float upp = 0.f;
    #pragma unroll 2
    for (int o = 0; o < 64; ++o) {
        const float* wkr = Wk + o*64;
        const float* wqr = Wq + o*64;
        float ko = bk[o], qo = bq[o];
        #pragma unroll
        for (int c = 0; c < 64; ++c) ko = fmaf(wkr[c], xr[c], ko);
        #pragma unroll
        for (int c = 0; c < 64; ++c) qo = fmaf(wqr[c], xr[c], qo);
        upp = fmaf(qo, ko, upp);
        const float* pq = PqwT + bsvb + o*16;
        const float* pk = PkwT + bsvb + o*16;
        #pragma unroll
        for (int i = 0; i < 16; ++i) {
            sp[i] = fmaf(pq[i], ko, sp[i]);
            tp[i] = fmaf(pk[i], qo, tp[i]);
        }
    }
    // center-row softmax weight
    float mc = upp;
    #pragma unroll
    for (int i = 0; i < 16; ++i) mc = fmaxf(mc, tp[i]);
    float ze = 0.f;
    #pragma unroll
    for (int i = 0; i < 16; ++i) ze += expf(tp[i] - mc);
    float ec = expf(upp - mc);
    float dcen = ec / (ze + ec);
    // window-row weights
    float d[16];
    #pragma unroll
    for (int i = 0; i < 16; ++i) {
        float premax = Pstat[bs48 + i*3 + 0];
        float preZ   = Pstat[bs48 + i*3 + 1];
        float diag   = Pstat[bs48 + i*3 + 2];
        float mi = fmaxf(premax, sp[i]);
        float zi = preZ * expf(premax - mi) + expf(sp[i] - mi);
        d[i] = expf(diag - mi) / zi;
    }
    // output: out_o = dcen*v_o + sum_i d_i * PvwT[o][i]
    float* xout = x + (size_t)p*64;
    #pragma unroll 1
    for (int o = 0; o < 64; o += 4) {
        float res[4];
        #pragma unroll
        for (int j = 0; j < 4; ++j) {
            const float* wvr = Wv + (o+j)*64;
            float vo = bv[o+j];
            #pragma unroll
            for (int c = 0; c < 64; ++c) vo = fmaf(wvr[c], xr[c], vo);
            float acc = dcen * vo;
            const float* pv = PvwT + bsvb + (o+j)*16;
            #pragma unroll
            for (int i = 0; i < 16; ++i) acc = fmaf(d[i], pv[i], acc);
            res[j] = acc;
        }
        if (pid >= 0) {
            float4 v4; v4.x = res[0]; v4.y = res[1]; v4.z = res[2]; v4.w = res[3];
            *(float4*)(xout + o) = v4;
        }
    }
}

// ---------------------------------------------------------------------------
// 6) partial sums (512 blocks x 4 waves, deterministic)
__global__ __launch_bounds__(256) void k_reduce(const float* __restrict__ x,
                                                float* __restrict__ part) {
    __shared__ float ls[4][64], lq[4][64];
    int t = threadIdx.x, q = t >> 6, c = t & 63;
    size_t base = ((size_t)blockIdx.x*128 + q*32) * 64;
    float s = 0.f, sq = 0.f;
    for (int r = 0; r < 32; ++r) {
        float v = x[base + r*64 + c];
        s += v; sq = fmaf(v, v, sq);
    }
    ls[q][c] = s; lq[q][c] = sq;
    __syncthreads();
    if (q == 0) {
        float S = ls[0][c] + ls[1][c] + ls[2][c] + ls[3][c];
        float Q = lq[0][c] + lq[1][c] + lq[2][c] + lq[3][c];
        part[blockIdx.x*64 + c] = S;
        part[512*64 + blockIdx.x*64 + c] = Q;
    }
}

// 7) finalize mean/var per channel
__global__ __launch_bounds__(256) void k_stats(const float* __restrict__ part,
                                               float* __restrict__ mv) {
    __shared__ float ls[4][64], lq[4][64];
    int t = threadIdx.x, q = t >> 6, c = t & 63;
    float s = 0.f, sq = 0.f;
    for (int r = q*128; r < q*128 + 128; ++r) {
        s  += part[r*64 + c];
        sq += part[512*64 + r*64 + c];
    }
    ls[q][c] = s; lq[q][c] = sq;
    __syncthreads();
    if (q == 0) {
        float S = ls[0][c] + ls[1][c] + ls[2][c] + ls[3][c];
        float Q = lq[0][c] + lq[1][c] + lq[2][c] + lq[3][c];
        float mean = S / (float)NPTS;
        float var  = Q / (float)NPTS - mean*mean;
        mv[c] = mean; mv[64 + c] = var;
    }
}

// ---------------------------------------------------------------------------
// 8) normalize + relu + residual; update fT; write out slice (B,C,N)
__global__ void k_norm(const float* __restrict__ x, float* __restrict__ fT,
                       const float* __restrict__ mv,
                       const float* __restrict__ gamma, const float* __restrict__ beta,
                       float* __restrict__ out, int l) {
    int blk = blockIdx.x;
    int b = blk / (NN/64);
    int n0 = (blk % (NN/64)) * 64;
    __shared__ float tile[64][65];   // [dn][c]
    int t = threadIdx.x;
    int c = t & 63, d0 = t >> 6;
    float mean = mv[c], var = mv[64+c];
    float inv = 1.0f / sqrtf(var + 1e-5f);
    float ga = gamma[c], be = beta[c];
    for (int i = 0; i < 16; ++i) {
        int dn = d0 + i*4;
        size_t pi = ((size_t)(b*NN + n0 + dn))*64 + c;
        float y = fT[pi] + fmaxf(ga * (x[pi] - mean) * inv + be, 0.f);
        fT[pi] = y;
        tile[dn][c] = y;
    }
    __syncthreads();
    int dn2 = t & 63, c0 = t >> 6;
    for (int i = 0; i < 16; ++i) {
        int cc = c0 + i*4;
        out[((size_t)(b*192 + l*64 + cc))*NN + n0 + dn2] = tile[dn2][cc];
    }
}

// ---------------------------------------------------------------------------
extern "C" void kernel_launch(void* const* d_in, const int* in_sizes, int n_in,
                              void* d_out, int out_size, void* d_ws, size_t ws_size,
                              hipStream_t stream) {
    const float* feature = (const float*)d_in[0];
    const int*   knn     = (const int*)d_in[1];
    const float* Wq = (const float*)d_in[2];
    const float* bq = (const float*)d_in[3];
    const float* Wk = (const float*)d_in[4];
    const float* bk = (const float*)d_in[5];
    const float* Wv = (const float*)d_in[6];
    const float* bv = (const float*)d_in[7];
    const float* gamma = (const float*)d_in[8];
    const float* beta  = (const float*)d_in[9];
    float* out = (float*)d_out;

    char* ws = (char*)d_ws;
    float* fT        = (float*)ws;                      // 16,777,216
    float* x         = (float*)(ws + 16777216);         // 16,777,216
    int*   s2buf     = (int*)  (ws + 33554432);         // 262,144
    int*   walkrows  = (int*)  (ws + 33816576);         // 1,024
    float* PqwT      = (float*)(ws + 33817600);         // 131,072
    float* PkwT      = (float*)(ws + 33948672);         // 131,072
    float* PvwT      = (float*)(ws + 34079744);         // 131,072
    float* Pstat     = (float*)(ws + 34210816);         // 6,144
    float* part      = (float*)(ws + 34216960);         // 262,144
    float* mv        = (float*)(ws + 34479104);         // 512
    int*   hist      = (int*)  (ws + 34479616);         // 128
    int*   head      = (int*)  (ws + 34479744);         // 128
    int*   wavebucket= (int*)  (ws + 34479872);         // 4,224
    int*   slotlist  = (int*)  (ws + 34484096);         // 270,336

    k_transpose<<<NB*(NN/64), 256, 0, stream>>>(feature, fT);
    k_s2<<<NPTS/64, 256, 0, stream>>>(fT, knn, s2buf);
    k_walk<<<1, 64, 0, stream>>>(s2buf, walkrows);
    k_init<<<NWAVES/4, 256, 0, stream>>>(slotlist, wavebucket, hist, head);
    k_hist<<<NPTS/256, 256, 0, stream>>>(s2buf, hist);
    k_offsets<<<1, 1, 0, stream>>>(hist, head, wavebucket);
    k_scatter<<<NPTS/256, 256, 0, stream>>>(s2buf, head, slotlist);

    for (int l = 0; l < 3; ++l) {
        k_precomp<<<32, 256, 0, stream>>>(fT, Wq + l*4096, bq + l*64,
                                          Wk + l*4096, bk + l*64,
                                          Wv + l*4096, bv + l*64,
                                          walkrows, PqwT, PkwT, PvwT, Pstat);
        k_layer<<<NWAVES/4, 256, 0, stream>>>(fT, Wq + l*4096, bq + l*64,
                                              Wk + l*4096, bk + l*64,
                                              Wv + l*4096, bv + l*64,
                                              PqwT, PkwT, PvwT, Pstat,
                                              slotlist, wavebucket, x);
        k_reduce<<<512, 256, 0, stream>>>(x, part);
        k_stats<<<1, 256, 0, stream>>>(part, mv);
        k_norm<<<NB*(NN/64), 256, 0, stream>>>(x, fT, mv, gamma + l*64, beta + l*64, out, l);
    }
}